// Round 2
// baseline (1205.919 us; speedup 1.0000x reference)
//
#include <hip/hip_runtime.h>
#include <hip/hip_bf16.h>

typedef unsigned int u32;

// ---------------- init: deg=1 (self loop), agg1=0, agg2=0 ----------------
__global__ __launch_bounds__(256) void k_init(int* __restrict__ degi,
                                              float* __restrict__ agg1,
                                              float* __restrict__ agg2, int N) {
    int t = blockIdx.x * 256 + threadIdx.x;
    if (t < N * 16) agg1[t] = 0.f;
    if (t < N * 2)  agg2[t] = 0.f;
    if (t < N)      degi[t] = 1;
}

// ---------------- degree: count dst occurrences ----------------
__global__ __launch_bounds__(256) void k_deg(const int* __restrict__ dst,
                                             int* __restrict__ degi, int E) {
    int e = blockIdx.x * 256 + threadIdx.x;
    if (e < E) atomicAdd(&degi[dst[e]], 1);
}

// ---------------- dinv = rsqrt(deg) (in place, int->float) ----------------
__global__ __launch_bounds__(256) void k_rsqrt(float* __restrict__ dinv, int N) {
    int i = blockIdx.x * 256 + threadIdx.x;
    if (i < N) {
        int d = ((const int*)dinv)[i];
        dinv[i] = rsqrtf((float)d);
    }
}

// ---------------- h[N,16] = x[N,128] @ W1[128,16] (fp32) ----------------
// One thread per node, 16 accumulators; W1 in LDS (uniform-address broadcast).
__global__ __launch_bounds__(256) void k_xw1(const float* __restrict__ x,
                                             const float* __restrict__ W1,
                                             float* __restrict__ h, int N) {
    __shared__ float w[128 * 16];
    int tid = threadIdx.x;
    for (int i = tid; i < 2048; i += 256) w[i] = W1[i];
    __syncthreads();
    int n = blockIdx.x * 256 + tid;
    if (n >= N) return;
    const float4* xr = (const float4*)(x + (size_t)n * 128);   // 32 x float4
    float acc[16];
    #pragma unroll
    for (int c = 0; c < 16; ++c) acc[c] = 0.f;
    #pragma unroll
    for (int i = 0; i < 32; ++i) {
        float4 v = xr[i];
        const float* w0 = w + (i * 4) * 16;
        #pragma unroll
        for (int c = 0; c < 16; ++c) {
            float a = acc[c];
            a = fmaf(v.x, w0[c],      a);
            a = fmaf(v.y, w0[16 + c], a);
            a = fmaf(v.z, w0[32 + c], a);
            a = fmaf(v.w, w0[48 + c], a);
            acc[c] = a;
        }
    }
    float4* ho = (float4*)(h + (size_t)n * 16);
    ho[0] = make_float4(acc[0],  acc[1],  acc[2],  acc[3]);
    ho[1] = make_float4(acc[4],  acc[5],  acc[6],  acc[7]);
    ho[2] = make_float4(acc[8],  acc[9],  acc[10], acc[11]);
    ho[3] = make_float4(acc[12], acc[13], acc[14], acc[15]);
}

// ---------------- layer-1 scatter: agg1[d] += h[s]*dinv[s]*dinv[d] ----------------
// 4 threads per edge, each handles one float4 of the 16 channels.
__global__ __launch_bounds__(256) void k_scat1(const int* __restrict__ ei,
                                               const float* __restrict__ dinv,
                                               const float* __restrict__ h,
                                               float* __restrict__ agg1, int E) {
    int t = blockIdx.x * 256 + threadIdx.x;
    int e = t >> 2, c = t & 3;
    if (e >= E) return;
    int s = ei[e], d = ei[E + e];
    float nrm = dinv[s] * dinv[d];
    float4 v = ((const float4*)(h + (size_t)s * 16))[c];
    float* ap = agg1 + (size_t)d * 16 + c * 4;
    unsafeAtomicAdd(ap + 0, v.x * nrm);
    unsafeAtomicAdd(ap + 1, v.y * nrm);
    unsafeAtomicAdd(ap + 2, v.z * nrm);
    unsafeAtomicAdd(ap + 3, v.w * nrm);
}

// ---------------- finalize 1: h1 = relu(agg1 + h*dinv^2 + b1) (in place) ----------------
__global__ __launch_bounds__(256) void k_fin1(float* __restrict__ agg1,
                                              const float* __restrict__ h,
                                              const float* __restrict__ dinv,
                                              const float* __restrict__ b1, int N) {
    int t = blockIdx.x * 256 + threadIdx.x;
    if (t >= N * 16) return;
    int n = t >> 4, j = t & 15;
    float di = dinv[n];
    float v = agg1[t] + h[t] * di * di + b1[j];
    agg1[t] = fmaxf(v, 0.f);
}

// ---------------- h2[N,2] = h1[N,16] @ W2[16,2] ----------------
__global__ __launch_bounds__(256) void k_h2(const float* __restrict__ h1,
                                            const float* __restrict__ W2,
                                            float* __restrict__ h2, int N) {
    int n = blockIdx.x * 256 + threadIdx.x;
    if (n >= N) return;
    const float4* r = (const float4*)(h1 + (size_t)n * 16);
    float a0 = 0.f, a1 = 0.f;
    #pragma unroll
    for (int i = 0; i < 4; ++i) {
        float4 v = r[i];
        a0 = fmaf(v.x, W2[(i*4+0)*2],   a0);
        a1 = fmaf(v.x, W2[(i*4+0)*2+1], a1);
        a0 = fmaf(v.y, W2[(i*4+1)*2],   a0);
        a1 = fmaf(v.y, W2[(i*4+1)*2+1], a1);
        a0 = fmaf(v.z, W2[(i*4+2)*2],   a0);
        a1 = fmaf(v.z, W2[(i*4+2)*2+1], a1);
        a0 = fmaf(v.w, W2[(i*4+3)*2],   a0);
        a1 = fmaf(v.w, W2[(i*4+3)*2+1], a1);
    }
    *(float2*)(h2 + (size_t)n * 2) = make_float2(a0, a1);
}

// ---------------- layer-2 scatter: agg2[d] += h2[s]*dinv[s]*dinv[d] ----------------
__global__ __launch_bounds__(256) void k_scat2(const int* __restrict__ ei,
                                               const float* __restrict__ dinv,
                                               const float* __restrict__ h2,
                                               float* __restrict__ agg2, int E) {
    int e = blockIdx.x * 256 + threadIdx.x;
    if (e >= E) return;
    int s = ei[e], d = ei[E + e];
    float nrm = dinv[s] * dinv[d];
    float2 v = *(const float2*)(h2 + (size_t)s * 2);
    unsafeAtomicAdd(agg2 + (size_t)d * 2 + 0, v.x * nrm);
    unsafeAtomicAdd(agg2 + (size_t)d * 2 + 1, v.y * nrm);
}

// ---------------- finalize 2: out = agg2 + h2*dinv^2 + b2 (fp32 out) ----------------
__global__ __launch_bounds__(256) void k_fin2(const float* __restrict__ agg2,
                                              const float* __restrict__ h2,
                                              const float* __restrict__ dinv,
                                              const float* __restrict__ b2,
                                              float* __restrict__ out, int N) {
    int t = blockIdx.x * 256 + threadIdx.x;
    if (t >= N * 2) return;
    int n = t >> 1, c = t & 1;
    float di = dinv[n];
    out[t] = agg2[t] + h2[t] * di * di + b2[c];
}

extern "C" void kernel_launch(void* const* d_in, const int* in_sizes, int n_in,
                              void* d_out, int out_size, void* d_ws, size_t ws_size,
                              hipStream_t stream) {
    const float* x  = (const float*)d_in[0];
    const int*   ei = (const int*)d_in[1];
    const float* W1 = (const float*)d_in[2];
    const float* b1 = (const float*)d_in[3];
    const float* W2 = (const float*)d_in[4];
    const float* b2 = (const float*)d_in[5];
    float* out = (float*)d_out;

    const int N = in_sizes[0] / 128;   // 100000
    const int E = in_sizes[1] / 2;     // 3200000

    char* ws = (char*)d_ws;
    size_t off = 0;
    auto alloc = [&](size_t bytes) {
        void* p = ws + off;
        off = (off + bytes + 255) & ~(size_t)255;
        return p;
    };
    float* dinv = (float*)alloc((size_t)N * 4);        // deg (int) then dinv (float)
    float* h    = (float*)alloc((size_t)N * 16 * 4);   // x @ W1
    float* agg1 = (float*)alloc((size_t)N * 16 * 4);   // layer-1 agg, then h1 in place
    float* h2   = (float*)alloc((size_t)N * 2 * 4);    // h1 @ W2
    float* agg2 = (float*)alloc((size_t)N * 2 * 4);    // layer-2 agg

    dim3 B(256);
    k_init <<<dim3((N * 16 + 255) / 256), B, 0, stream>>>((int*)dinv, agg1, agg2, N);
    k_deg  <<<dim3((E + 255) / 256),       B, 0, stream>>>(ei + E, (int*)dinv, E);
    k_rsqrt<<<dim3((N + 255) / 256),       B, 0, stream>>>(dinv, N);
    k_xw1  <<<dim3((N + 255) / 256),       B, 0, stream>>>(x, W1, h, N);
    k_scat1<<<dim3((E * 4 + 255) / 256),   B, 0, stream>>>(ei, dinv, h, agg1, E);
    k_fin1 <<<dim3((N * 16 + 255) / 256),  B, 0, stream>>>(agg1, h, dinv, b1, N);
    k_h2   <<<dim3((N + 255) / 256),       B, 0, stream>>>(agg1, W2, h2, N);
    k_scat2<<<dim3((E + 255) / 256),       B, 0, stream>>>(ei, dinv, h2, agg2, E);
    k_fin2 <<<dim3((N * 2 + 255) / 256),   B, 0, stream>>>(agg2, h2, dinv, b2, out, N);
}

// Round 3
// 642.790 us; speedup vs baseline: 1.8761x; 1.8761x over previous
//
#include <hip/hip_runtime.h>
#include <hip/hip_bf16.h>

// GCN 2-layer forward, N=100000 nodes, E=3200000 edges, 128->16->2.
// Strategy: no f32 scatter atomics (they write through to HBM at 16B/atomic,
// 800 MB/launch measured in round 2). Build CSR-by-dst via counting sort,
// then aggregate as gathers. Algebra: hs = (x@W1)*dinv;
//   h1[d]  = relu(dinv[d]*(sum_nbr hs[s] + hs[d]) + b1)   (gather)
//   h2s[d] = (h1[d]@W2)*dinv[d]                           (fused into gather epilogue)
//   out[d] = dinv[d]*(sum_nbr h2s[s] + h2s[d]) + b2       (gather)

// ---------------- zero degree ----------------
__global__ __launch_bounds__(256) void k_zero(int* __restrict__ deg, int N) {
    int i = blockIdx.x * 256 + threadIdx.x;
    if (i < N) deg[i] = 0;
}

// ---------------- in-degree count (edges only; self-loop folded later) ----------------
__global__ __launch_bounds__(256) void k_deg(const int* __restrict__ dst,
                                             int* __restrict__ deg, int E) {
    int e = blockIdx.x * 256 + threadIdx.x;
    if (e < E) atomicAdd(&deg[dst[e]], 1);
}

// ---------------- scan stage 1: per-block exclusive scan of deg ----------------
__global__ __launch_bounds__(256) void k_scan1(const int* __restrict__ deg,
                                               int* __restrict__ rp,
                                               int* __restrict__ bsum, int N) {
    __shared__ int s[256];
    int tid = threadIdx.x;
    int i = blockIdx.x * 256 + tid;
    int v = (i < N) ? deg[i] : 0;
    s[tid] = v;
    __syncthreads();
    for (int o = 1; o < 256; o <<= 1) {
        int t = (tid >= o) ? s[tid - o] : 0;
        __syncthreads();
        s[tid] += t;
        __syncthreads();
    }
    if (i < N) rp[i] = s[tid] - v;          // exclusive within block
    if (tid == 255) bsum[blockIdx.x] = s[255];
}

// ---------------- scan stage 2: single block scans the block sums ----------------
// NB = ceil(N/256) = 391 for N=100000; requires NB <= 512.
__global__ __launch_bounds__(512) void k_scan2(int* __restrict__ bsum, int NB) {
    __shared__ int s[512];
    int tid = threadIdx.x;
    int v = (tid < NB) ? bsum[tid] : 0;
    s[tid] = v;
    __syncthreads();
    for (int o = 1; o < 512; o <<= 1) {
        int t = (tid >= o) ? s[tid - o] : 0;
        __syncthreads();
        s[tid] += t;
        __syncthreads();
    }
    if (tid < NB) bsum[tid] = s[tid] - v;   // exclusive
}

// ---------------- scan stage 3: finalize row_ptr, cursor, dinv ----------------
__global__ __launch_bounds__(256) void k_scan3(int* __restrict__ rp,
                                               const int* __restrict__ bsum,
                                               int* __restrict__ cur,
                                               const int* __restrict__ deg,
                                               float* __restrict__ dinv, int N) {
    int i = blockIdx.x * 256 + threadIdx.x;
    if (i >= N) return;
    int r = rp[i] + bsum[i >> 8];
    rp[i] = r;
    cur[i] = r;
    dinv[i] = rsqrtf((float)(deg[i] + 1));  // +1: self loop
    if (i == N - 1) rp[N] = r + deg[i];
}

// ---------------- CSR fill: csr[pos] = src, bucketed by dst ----------------
__global__ __launch_bounds__(256) void k_fill(const int* __restrict__ ei,
                                              int* __restrict__ cur,
                                              int* __restrict__ csr, int E) {
    int e = blockIdx.x * 256 + threadIdx.x;
    if (e >= E) return;
    int s = ei[e], d = ei[E + e];
    int pos = atomicAdd(&cur[d], 1);
    csr[pos] = s;
}

// ---------------- hs[N,16] = (x[N,128] @ W1[128,16]) * dinv ----------------
// 4 threads per node, 4 channels each; W1 staged in LDS, read as float4.
__global__ __launch_bounds__(256) void k_xw1(const float* __restrict__ x,
                                             const float* __restrict__ W1,
                                             const float* __restrict__ dinv,
                                             float* __restrict__ hs, int N) {
    __shared__ float w[128 * 16];
    int tid = threadIdx.x;
    for (int i = tid; i < 2048; i += 256) w[i] = W1[i];
    __syncthreads();
    int t = blockIdx.x * 256 + tid;
    int n = t >> 2, q = t & 3;
    if (n >= N) return;
    const float4* xr = (const float4*)(x + (size_t)n * 128);
    const float4* w4 = (const float4*)w;    // w4[f*4+q] = W1[f][4q..4q+3]
    float ax = 0.f, ay = 0.f, az = 0.f, aw = 0.f;
    #pragma unroll
    for (int i = 0; i < 32; ++i) {
        float4 u = xr[i];
        int fb = i * 4;
        float4 wa = w4[(fb + 0) * 4 + q];
        float4 wb = w4[(fb + 1) * 4 + q];
        float4 wc = w4[(fb + 2) * 4 + q];
        float4 wd = w4[(fb + 3) * 4 + q];
        ax = fmaf(u.x, wa.x, ax); ay = fmaf(u.x, wa.y, ay);
        az = fmaf(u.x, wa.z, az); aw = fmaf(u.x, wa.w, aw);
        ax = fmaf(u.y, wb.x, ax); ay = fmaf(u.y, wb.y, ay);
        az = fmaf(u.y, wb.z, az); aw = fmaf(u.y, wb.w, aw);
        ax = fmaf(u.z, wc.x, ax); ay = fmaf(u.z, wc.y, ay);
        az = fmaf(u.z, wc.z, az); aw = fmaf(u.z, wc.w, aw);
        ax = fmaf(u.w, wd.x, ax); ay = fmaf(u.w, wd.y, ay);
        az = fmaf(u.w, wd.z, az); aw = fmaf(u.w, wd.w, aw);
    }
    float di = dinv[n];
    ((float4*)(hs + (size_t)n * 16))[q] =
        make_float4(ax * di, ay * di, az * di, aw * di);
}

// ---------------- fused layer-1 gather + ReLU + W2 projection ----------------
// One wave per node: lanes = 16 channels x 4 edge groups.
__global__ __launch_bounds__(256) void k_agg1h2(const int* __restrict__ rp,
                                                const int* __restrict__ csr,
                                                const float* __restrict__ hs,
                                                const float* __restrict__ dinv,
                                                const float* __restrict__ W2,
                                                const float* __restrict__ b1,
                                                float* __restrict__ h2s, int N) {
    int wid = blockIdx.x * 4 + (threadIdx.x >> 6);   // node
    int lane = threadIdx.x & 63;
    if (wid >= N) return;
    int beg = rp[wid], end = rp[wid + 1];
    int c = lane & 15, g = lane >> 4;                // channel, edge-group
    float acc = 0.f;
    for (int j = beg + g; j < end; j += 4) {
        int s = csr[j];
        acc += hs[(size_t)s * 16 + c];
    }
    acc += __shfl_xor(acc, 16);
    acc += __shfl_xor(acc, 32);                      // all lanes: full sum for channel c
    float di = dinv[wid];
    float v = fmaxf(fmaf(di, acc + hs[(size_t)wid * 16 + c], b1[c]), 0.f); // h1[wid][c]
    // project: h2s[wid] = (h1 @ W2) * di   (reduce 16 channels via shuffles)
    float p0 = v * W2[2 * c];
    float p1 = v * W2[2 * c + 1];
    p0 += __shfl_xor(p0, 1); p1 += __shfl_xor(p1, 1);
    p0 += __shfl_xor(p0, 2); p1 += __shfl_xor(p1, 2);
    p0 += __shfl_xor(p0, 4); p1 += __shfl_xor(p1, 4);
    p0 += __shfl_xor(p0, 8); p1 += __shfl_xor(p1, 8);
    if (lane == 0)
        *(float2*)(h2s + (size_t)wid * 2) = make_float2(p0 * di, p1 * di);
}

// ---------------- layer-2 gather -> out ----------------
// One wave per node: lanes = 2 channels x 32 edge groups.
__global__ __launch_bounds__(256) void k_agg2(const int* __restrict__ rp,
                                              const int* __restrict__ csr,
                                              const float* __restrict__ h2s,
                                              const float* __restrict__ dinv,
                                              const float* __restrict__ b2,
                                              float* __restrict__ out, int N) {
    int wid = blockIdx.x * 4 + (threadIdx.x >> 6);
    int lane = threadIdx.x & 63;
    if (wid >= N) return;
    int beg = rp[wid], end = rp[wid + 1];
    int c = lane & 1, g = lane >> 1;
    float acc = 0.f;
    for (int j = beg + g; j < end; j += 32) {
        int s = csr[j];
        acc += h2s[(size_t)s * 2 + c];
    }
    acc += __shfl_xor(acc, 2);
    acc += __shfl_xor(acc, 4);
    acc += __shfl_xor(acc, 8);
    acc += __shfl_xor(acc, 16);
    acc += __shfl_xor(acc, 32);
    if (lane < 2) {
        float di = dinv[wid];
        out[(size_t)wid * 2 + lane] =
            fmaf(di, acc + h2s[(size_t)wid * 2 + lane], b2[lane]);
    }
}

extern "C" void kernel_launch(void* const* d_in, const int* in_sizes, int n_in,
                              void* d_out, int out_size, void* d_ws, size_t ws_size,
                              hipStream_t stream) {
    const float* x  = (const float*)d_in[0];
    const int*   ei = (const int*)d_in[1];
    const float* W1 = (const float*)d_in[2];
    const float* b1 = (const float*)d_in[3];
    const float* W2 = (const float*)d_in[4];
    const float* b2 = (const float*)d_in[5];
    float* out = (float*)d_out;

    const int N = in_sizes[0] / 128;   // 100000
    const int E = in_sizes[1] / 2;     // 3200000
    const int NB = (N + 255) / 256;    // scan blocks (391; must be <= 512)

    char* ws = (char*)d_ws;
    size_t off = 0;
    auto alloc = [&](size_t bytes) {
        void* p = ws + off;
        off = (off + bytes + 255) & ~(size_t)255;
        return p;
    };
    int*   deg  = (int*)alloc((size_t)N * 4);
    int*   rp   = (int*)alloc((size_t)(N + 1) * 4);
    int*   cur  = (int*)alloc((size_t)N * 4);
    int*   bsum = (int*)alloc((size_t)NB * 4);
    float* dinv = (float*)alloc((size_t)N * 4);
    float* hs   = (float*)alloc((size_t)N * 16 * 4);
    float* h2s  = (float*)alloc((size_t)N * 2 * 4);
    int*   csr  = (int*)alloc((size_t)E * 4);

    dim3 B(256);
    k_zero  <<<dim3((N + 255) / 256),     B, 0, stream>>>(deg, N);
    k_deg   <<<dim3((E + 255) / 256),     B, 0, stream>>>(ei + E, deg, E);
    k_scan1 <<<dim3(NB),                  B, 0, stream>>>(deg, rp, bsum, N);
    k_scan2 <<<dim3(1),           dim3(512), 0, stream>>>(bsum, NB);
    k_scan3 <<<dim3(NB),                  B, 0, stream>>>(rp, bsum, cur, deg, dinv, N);
    k_fill  <<<dim3((E + 255) / 256),     B, 0, stream>>>(ei, cur, csr, E);
    k_xw1   <<<dim3((N * 4 + 255) / 256), B, 0, stream>>>(x, W1, dinv, hs, N);
    k_agg1h2<<<dim3((N + 3) / 4),         B, 0, stream>>>(rp, csr, hs, dinv, W2, b1, h2s, N);
    k_agg2  <<<dim3((N + 3) / 4),         B, 0, stream>>>(rp, csr, h2s, dinv, b2, out, N);
}

// Round 4
// 295.995 us; speedup vs baseline: 4.0741x; 2.1716x over previous
//
#include <hip/hip_runtime.h>

// GCN 2-layer forward, N=100000, E=3200000, 128->16->2.
// Round-4: CSR build via 2-level counting sort with ZERO scattered global
// stores (round-3 k_fill wrote 194 MB HBM for a 12.8 MB array: 4B scattered
// stores -> 64B line write-through). Buckets: b = dst >> 8 (256 dsts each).
//   k_count   : per-block LDS histogram -> global bucket counts
//   k_bscan   : scan bucket counts -> bases
//   k_scatter : append packed (dlow<<24|src) into bucket regions (dense runs)
//   k_fillB   : per-bucket LDS sort by dst -> write csr back IN PLACE,
//               coalesced; emits rp and dinv (deg falls out free).
// Aggregation (unchanged): hs = (x@W1)*dinv;
//   h1[d]  = relu(dinv[d]*(sum_nbr hs + hs[d]) + b1)     gather, fused W2
//   out[d] = dinv[d]*(sum_nbr h2s + h2s[d]) + b2         gather

#define EPB 8192     // edges per partition block
#define CAP 16384    // LDS src slots per bucket (mean 8192, sigma ~90)

// ---------------- zero bucket counters ----------------
__global__ __launch_bounds__(512) void k_bzero(int* __restrict__ gcnt, int NBUK) {
    int t = threadIdx.x;
    if (t < NBUK) gcnt[t] = 0;
}

// ---------------- bucket histogram ----------------
__global__ __launch_bounds__(256) void k_count(const int* __restrict__ dst,
                                               int* __restrict__ gcnt,
                                               int E, int NBUK) {
    __shared__ int hist[512];
    int tid = threadIdx.x;
    for (int i = tid; i < NBUK; i += 256) hist[i] = 0;
    __syncthreads();
    int base = blockIdx.x * EPB;
    int end = base + EPB; if (end > E) end = E;
    for (int e = base + tid; e < end; e += 256)
        atomicAdd(&hist[dst[e] >> 8], 1);
    __syncthreads();
    for (int i = tid; i < NBUK; i += 256)
        if (hist[i]) atomicAdd(&gcnt[i], hist[i]);
}

// ---------------- scan bucket counts -> bases (single block) ----------------
__global__ __launch_bounds__(512) void k_bscan(const int* __restrict__ gcnt,
                                               int* __restrict__ gbase,
                                               int* __restrict__ gcur,
                                               int* __restrict__ rp,
                                               int N, int E, int NBUK) {
    __shared__ int s[512];
    int tid = threadIdx.x;
    int v = (tid < NBUK) ? gcnt[tid] : 0;
    s[tid] = v;
    __syncthreads();
    for (int o = 1; o < 512; o <<= 1) {
        int t = (tid >= o) ? s[tid - o] : 0;
        __syncthreads();
        s[tid] += t;
        __syncthreads();
    }
    if (tid < NBUK) { int b = s[tid] - v; gbase[tid] = b; gcur[tid] = b; }
    if (tid == 0) rp[N] = E;
}

// ---------------- partition edges into bucket regions ----------------
__global__ __launch_bounds__(256) void k_scatter(const int* __restrict__ ei,
                                                 int* __restrict__ gcur,
                                                 unsigned* __restrict__ part,
                                                 int E, int NBUK) {
    __shared__ int hist[512];
    int tid = threadIdx.x;
    for (int i = tid; i < NBUK; i += 256) hist[i] = 0;
    __syncthreads();
    int base = blockIdx.x * EPB;
    int end = base + EPB; if (end > E) end = E;
    for (int e = base + tid; e < end; e += 256)
        atomicAdd(&hist[ei[E + e] >> 8], 1);
    __syncthreads();
    // reserve one contiguous run per (block,bucket); hist becomes the cursor
    for (int i = tid; i < NBUK; i += 256) {
        int c = hist[i];
        hist[i] = c ? atomicAdd(&gcur[i], c) : 0;
    }
    __syncthreads();
    for (int e = base + tid; e < end; e += 256) {
        int s = ei[e], d = ei[E + e];
        int pos = atomicAdd(&hist[d >> 8], 1);
        part[pos] = ((unsigned)(d & 255) << 24) | (unsigned)s;  // N < 2^24
    }
}

// ---------------- per-bucket sort by dst; csr written IN PLACE ----------------
__global__ __launch_bounds__(256) void k_fillB(unsigned* __restrict__ part,
                                               const int* __restrict__ gbase,
                                               const int* __restrict__ gcnt,
                                               int* __restrict__ rp,
                                               float* __restrict__ dinv, int N) {
    __shared__ int hist[256];
    __shared__ int ofs[256];
    __shared__ unsigned srcbuf[CAP];
    int b = blockIdx.x, tid = threadIdx.x;
    int base = gbase[b], cnt = gcnt[b];
    hist[tid] = 0;
    __syncthreads();
    for (int j = tid; j < cnt; j += 256)
        atomicAdd(&hist[part[base + j] >> 24], 1);
    __syncthreads();
    int v = hist[tid];                 // deg of dst (b*256 + tid)
    ofs[tid] = v;
    __syncthreads();
    for (int o = 1; o < 256; o <<= 1) {
        int t = (tid >= o) ? ofs[tid - o] : 0;
        __syncthreads();
        ofs[tid] += t;
        __syncthreads();
    }
    int excl = ofs[tid] - v;           // local exclusive offset for dst tid
    hist[tid] = excl;                  // reuse hist as scatter cursor
    __syncthreads();
    for (int j = tid; j < cnt; j += 256) {
        unsigned pv = part[base + j];
        int pos = atomicAdd(&hist[pv >> 24], 1);
        if (pos < CAP) srcbuf[pos] = pv & 0xFFFFFFu;
    }
    __syncthreads();
    for (int j = tid; j < cnt; j += 256)
        part[base + j] = srcbuf[j];    // coalesced write-back: csr ids by dst
    int d = b * 256 + tid;
    if (d < N) {
        rp[d] = base + excl;
        dinv[d] = rsqrtf((float)(v + 1));   // +1 self loop
    }
}

// ---------------- hs[N,16] = (x[N,128] @ W1[128,16]) * dinv ----------------
__global__ __launch_bounds__(256) void k_xw1(const float* __restrict__ x,
                                             const float* __restrict__ W1,
                                             const float* __restrict__ dinv,
                                             float* __restrict__ hs, int N) {
    __shared__ float w[128 * 16];
    int tid = threadIdx.x;
    for (int i = tid; i < 2048; i += 256) w[i] = W1[i];
    __syncthreads();
    int t = blockIdx.x * 256 + tid;
    int n = t >> 2, q = t & 3;
    if (n >= N) return;
    const float4* xr = (const float4*)(x + (size_t)n * 128);
    const float4* w4 = (const float4*)w;    // w4[f*4+q] = W1[f][4q..4q+3]
    float ax = 0.f, ay = 0.f, az = 0.f, aw = 0.f;
    #pragma unroll
    for (int i = 0; i < 32; ++i) {
        float4 u = xr[i];
        int fb = i * 4;
        float4 wa = w4[(fb + 0) * 4 + q];
        float4 wb = w4[(fb + 1) * 4 + q];
        float4 wc = w4[(fb + 2) * 4 + q];
        float4 wd = w4[(fb + 3) * 4 + q];
        ax = fmaf(u.x, wa.x, ax); ay = fmaf(u.x, wa.y, ay);
        az = fmaf(u.x, wa.z, az); aw = fmaf(u.x, wa.w, aw);
        ax = fmaf(u.y, wb.x, ax); ay = fmaf(u.y, wb.y, ay);
        az = fmaf(u.y, wb.z, az); aw = fmaf(u.y, wb.w, aw);
        ax = fmaf(u.z, wc.x, ax); ay = fmaf(u.z, wc.y, ay);
        az = fmaf(u.z, wc.z, az); aw = fmaf(u.z, wc.w, aw);
        ax = fmaf(u.w, wd.x, ax); ay = fmaf(u.w, wd.y, ay);
        az = fmaf(u.w, wd.z, az); aw = fmaf(u.w, wd.w, aw);
    }
    float di = dinv[n];
    ((float4*)(hs + (size_t)n * 16))[q] =
        make_float4(ax * di, ay * di, az * di, aw * di);
}

// ---------------- fused layer-1 gather + ReLU + W2 projection ----------------
// One wave per node: lanes = 16 channels x 4 edge groups.
__global__ __launch_bounds__(256) void k_agg1h2(const int* __restrict__ rp,
                                                const int* __restrict__ csr,
                                                const float* __restrict__ hs,
                                                const float* __restrict__ dinv,
                                                const float* __restrict__ W2,
                                                const float* __restrict__ b1,
                                                float* __restrict__ h2s, int N) {
    int wid = blockIdx.x * 4 + (threadIdx.x >> 6);
    int lane = threadIdx.x & 63;
    if (wid >= N) return;
    int beg = rp[wid], end = rp[wid + 1];
    int c = lane & 15, g = lane >> 4;
    float acc = 0.f;
    for (int j = beg + g; j < end; j += 4) {
        int s = csr[j];
        acc += hs[(size_t)s * 16 + c];
    }
    acc += __shfl_xor(acc, 16);
    acc += __shfl_xor(acc, 32);
    float di = dinv[wid];
    float v = fmaxf(fmaf(di, acc + hs[(size_t)wid * 16 + c], b1[c]), 0.f);
    float p0 = v * W2[2 * c];
    float p1 = v * W2[2 * c + 1];
    p0 += __shfl_xor(p0, 1); p1 += __shfl_xor(p1, 1);
    p0 += __shfl_xor(p0, 2); p1 += __shfl_xor(p1, 2);
    p0 += __shfl_xor(p0, 4); p1 += __shfl_xor(p1, 4);
    p0 += __shfl_xor(p0, 8); p1 += __shfl_xor(p1, 8);
    if (lane == 0)
        *(float2*)(h2s + (size_t)wid * 2) = make_float2(p0 * di, p1 * di);
}

// ---------------- layer-2 gather -> out ----------------
__global__ __launch_bounds__(256) void k_agg2(const int* __restrict__ rp,
                                              const int* __restrict__ csr,
                                              const float* __restrict__ h2s,
                                              const float* __restrict__ dinv,
                                              const float* __restrict__ b2,
                                              float* __restrict__ out, int N) {
    int wid = blockIdx.x * 4 + (threadIdx.x >> 6);
    int lane = threadIdx.x & 63;
    if (wid >= N) return;
    int beg = rp[wid], end = rp[wid + 1];
    int c = lane & 1, g = lane >> 1;
    float acc = 0.f;
    for (int j = beg + g; j < end; j += 32) {
        int s = csr[j];
        acc += h2s[(size_t)s * 2 + c];
    }
    acc += __shfl_xor(acc, 2);
    acc += __shfl_xor(acc, 4);
    acc += __shfl_xor(acc, 8);
    acc += __shfl_xor(acc, 16);
    acc += __shfl_xor(acc, 32);
    if (lane < 2) {
        float di = dinv[wid];
        out[(size_t)wid * 2 + lane] =
            fmaf(di, acc + h2s[(size_t)wid * 2 + lane], b2[lane]);
    }
}

extern "C" void kernel_launch(void* const* d_in, const int* in_sizes, int n_in,
                              void* d_out, int out_size, void* d_ws, size_t ws_size,
                              hipStream_t stream) {
    const float* x  = (const float*)d_in[0];
    const int*   ei = (const int*)d_in[1];
    const float* W1 = (const float*)d_in[2];
    const float* b1 = (const float*)d_in[3];
    const float* W2 = (const float*)d_in[4];
    const float* b2 = (const float*)d_in[5];
    float* out = (float*)d_out;

    const int N = in_sizes[0] / 128;     // 100000
    const int E = in_sizes[1] / 2;       // 3200000
    const int NBUK = (N + 255) / 256;    // 391 (must be <= 512)
    const int NPB  = (E + EPB - 1) / EPB;// 391 partition blocks

    char* ws = (char*)d_ws;
    size_t off = 0;
    auto alloc = [&](size_t bytes) {
        void* p = ws + off;
        off = (off + bytes + 255) & ~(size_t)255;
        return p;
    };
    unsigned* part = (unsigned*)alloc((size_t)E * 4);      // partition buf == csr
    int*   rp    = (int*)alloc((size_t)(N + 1) * 4);
    float* dinv  = (float*)alloc((size_t)N * 4);
    float* hs    = (float*)alloc((size_t)N * 16 * 4);
    float* h2s   = (float*)alloc((size_t)N * 2 * 4);
    int*   gcnt  = (int*)alloc((size_t)NBUK * 4);
    int*   gbase = (int*)alloc((size_t)NBUK * 4);
    int*   gcur  = (int*)alloc((size_t)NBUK * 4);

    dim3 B(256);
    k_bzero  <<<dim3(1),          dim3(512), 0, stream>>>(gcnt, NBUK);
    k_count  <<<dim3(NPB),                B, 0, stream>>>(ei + E, gcnt, E, NBUK);
    k_bscan  <<<dim3(1),          dim3(512), 0, stream>>>(gcnt, gbase, gcur, rp, N, E, NBUK);
    k_scatter<<<dim3(NPB),                B, 0, stream>>>(ei, gcur, part, E, NBUK);
    k_fillB  <<<dim3(NBUK),               B, 0, stream>>>(part, gbase, gcnt, rp, dinv, N);
    k_xw1    <<<dim3((N * 4 + 255) / 256),B, 0, stream>>>(x, W1, dinv, hs, N);
    k_agg1h2 <<<dim3((N + 3) / 4),        B, 0, stream>>>(rp, (int*)part, hs, dinv, W2, b1, h2s, N);
    k_agg2   <<<dim3((N + 3) / 4),        B, 0, stream>>>(rp, (int*)part, h2s, dinv, b2, out, N);
}

// Round 5
// 249.557 us; speedup vs baseline: 4.8322x; 1.1861x over previous
//
#include <hip/hip_runtime.h>

// GCN 2-layer forward, N=100000, E=3200000, 128->16->2.
// Round-5:
//  - hs stored as bf16 (3.2 MB: fits per-XCD 4MB L2 -> gather L2-hits;
//    round-4 measured 98.5 MB FETCH on fp32 hs = 6.4 MB working set)
//  - k_agg1h2: 4 lanes/edge x uint2 (full 32B row per 4 lanes), 16 edge
//    groups/wave -> 4x MLP, deg/16 iters
//  - k_scatter: block-local LDS counting sort -> coalesced run writes
//    (kills the last scattered-4B-store kernel)
// Algebra: hs = (x@W1)*dinv;
//   h1[d]  = relu(dinv[d]*(sum_nbr hs + hs[d]) + b1)   gather, W2 fused
//   out[d] = dinv[d]*(sum_nbr h2s + h2s[d]) + b2       gather

#define EPB 8192     // edges per partition block
#define CAP 16384    // LDS slots per bucket in k_fillB (mean 8192, sigma~90)

typedef unsigned int u32;
typedef unsigned short u16;

__device__ __forceinline__ float bflo(u32 u) { return __uint_as_float(u << 16); }
__device__ __forceinline__ float bfhi(u32 u) { return __uint_as_float(u & 0xffff0000u); }
__device__ __forceinline__ u32 pack_bf2(float a, float b) {   // RNE
    u32 ua = __float_as_uint(a); ua = (ua + 0x7fffu + ((ua >> 16) & 1u)) >> 16;
    u32 ub = __float_as_uint(b); ub = (ub + 0x7fffu + ((ub >> 16) & 1u)) >> 16;
    return ua | (ub << 16);
}

// ---------------- zero bucket counters ----------------
__global__ __launch_bounds__(512) void k_bzero(int* __restrict__ gcnt, int NBUK) {
    int t = threadIdx.x;
    if (t < NBUK) gcnt[t] = 0;
}

// ---------------- bucket histogram ----------------
__global__ __launch_bounds__(256) void k_count(const int* __restrict__ dst,
                                               int* __restrict__ gcnt,
                                               int E, int NBUK) {
    __shared__ int hist[512];
    int tid = threadIdx.x;
    for (int i = tid; i < NBUK; i += 256) hist[i] = 0;
    __syncthreads();
    int base = blockIdx.x * EPB;
    int end = base + EPB; if (end > E) end = E;
    for (int e = base + tid; e < end; e += 256)
        atomicAdd(&hist[dst[e] >> 8], 1);
    __syncthreads();
    for (int i = tid; i < NBUK; i += 256)
        if (hist[i]) atomicAdd(&gcnt[i], hist[i]);
}

// ---------------- scan bucket counts -> bases (single block) ----------------
__global__ __launch_bounds__(512) void k_bscan(const int* __restrict__ gcnt,
                                               int* __restrict__ gbase,
                                               int* __restrict__ gcur,
                                               int* __restrict__ rp,
                                               int N, int E, int NBUK) {
    __shared__ int s[512];
    int tid = threadIdx.x;
    int v = (tid < NBUK) ? gcnt[tid] : 0;
    s[tid] = v;
    __syncthreads();
    for (int o = 1; o < 512; o <<= 1) {
        int t = (tid >= o) ? s[tid - o] : 0;
        __syncthreads();
        s[tid] += t;
        __syncthreads();
    }
    if (tid < NBUK) { int b = s[tid] - v; gbase[tid] = b; gcur[tid] = b; }
    if (tid == 0) rp[N] = E;
}

// ---------------- partition: block-local sort by bucket, coalesced writes ----
__global__ __launch_bounds__(512) void k_scatter(const int* __restrict__ ei,
                                                 int* __restrict__ gcur,
                                                 u32* __restrict__ part,
                                                 int E, int NBUK) {
    __shared__ int hist[512];   // counts -> placement cursors
    __shared__ int lofs[512];   // local exclusive offsets (search key)
    __shared__ int rbase[512];  // global addr = rbase[b] + local slot j
    __shared__ u32 buf[EPB];
    int tid = threadIdx.x;
    hist[tid] = 0;
    __syncthreads();
    int base = blockIdx.x * EPB;
    int end = base + EPB; if (end > E) end = E;
    for (int e = base + tid; e < end; e += 512)
        atomicAdd(&hist[ei[E + e] >> 8], 1);
    __syncthreads();
    int v = hist[tid];
    lofs[tid] = v;
    __syncthreads();
    for (int o = 1; o < 512; o <<= 1) {
        int t = (tid >= o) ? lofs[tid - o] : 0;
        __syncthreads();
        lofs[tid] += t;
        __syncthreads();
    }
    int excl = lofs[tid] - v;
    int rb = 0;
    if (tid < NBUK && v > 0) rb = atomicAdd(&gcur[tid], v);  // reserve run
    __syncthreads();
    rbase[tid] = rb - excl;
    hist[tid] = excl;           // placement cursor
    lofs[tid] = excl;           // exclusive offsets for binary search
    __syncthreads();
    for (int e = base + tid; e < end; e += 512) {
        int s = ei[e], d = ei[E + e];
        int pos = atomicAdd(&hist[d >> 8], 1);
        buf[pos] = ((u32)(d & 255) << 24) | (u32)s;          // N < 2^24
    }
    __syncthreads();
    int cnt = end - base;
    for (int j = tid; j < cnt; j += 512) {
        int lo = 0, hi = NBUK - 1;                            // last b: lofs[b] <= j
        while (lo < hi) {
            int mid = (lo + hi + 1) >> 1;
            if (lofs[mid] <= j) lo = mid; else hi = mid - 1;
        }
        part[rbase[lo] + j] = buf[j];                         // ~coalesced runs
    }
}

// ---------------- per-bucket sort by dst; csr written IN PLACE ----------------
__global__ __launch_bounds__(256) void k_fillB(u32* __restrict__ part,
                                               const int* __restrict__ gbase,
                                               const int* __restrict__ gcnt,
                                               int* __restrict__ rp,
                                               float* __restrict__ dinv, int N) {
    __shared__ int hist[256];
    __shared__ int ofs[256];
    __shared__ u32 srcbuf[CAP];
    int b = blockIdx.x, tid = threadIdx.x;
    int base = gbase[b], cnt = gcnt[b];
    hist[tid] = 0;
    __syncthreads();
    for (int j = tid; j < cnt; j += 256)
        atomicAdd(&hist[part[base + j] >> 24], 1);
    __syncthreads();
    int v = hist[tid];                 // deg of dst (b*256 + tid)
    ofs[tid] = v;
    __syncthreads();
    for (int o = 1; o < 256; o <<= 1) {
        int t = (tid >= o) ? ofs[tid - o] : 0;
        __syncthreads();
        ofs[tid] += t;
        __syncthreads();
    }
    int excl = ofs[tid] - v;
    hist[tid] = excl;                  // scatter cursor
    __syncthreads();
    for (int j = tid; j < cnt; j += 256) {
        u32 pv = part[base + j];
        int pos = atomicAdd(&hist[pv >> 24], 1);
        if (pos < CAP) srcbuf[pos] = pv & 0xFFFFFFu;
    }
    __syncthreads();
    for (int j = tid; j < cnt; j += 256)
        part[base + j] = srcbuf[j];    // coalesced write-back
    int d = b * 256 + tid;
    if (d < N) {
        rp[d] = base + excl;
        dinv[d] = rsqrtf((float)(v + 1));   // +1 self loop
    }
}

// ---------------- hs[N,16](bf16) = (x[N,128] @ W1[128,16]) * dinv -------------
__global__ __launch_bounds__(256) void k_xw1(const float* __restrict__ x,
                                             const float* __restrict__ W1,
                                             const float* __restrict__ dinv,
                                             u16* __restrict__ hs, int N) {
    __shared__ float w[128 * 16];
    int tid = threadIdx.x;
    for (int i = tid; i < 2048; i += 256) w[i] = W1[i];
    __syncthreads();
    int t = blockIdx.x * 256 + tid;
    int n = t >> 2, q = t & 3;
    if (n >= N) return;
    const float4* xr = (const float4*)(x + (size_t)n * 128);
    const float4* w4 = (const float4*)w;    // w4[f*4+q] = W1[f][4q..4q+3]
    float ax = 0.f, ay = 0.f, az = 0.f, aw = 0.f;
    #pragma unroll
    for (int i = 0; i < 32; ++i) {
        float4 u = xr[i];
        int fb = i * 4;
        float4 wa = w4[(fb + 0) * 4 + q];
        float4 wb = w4[(fb + 1) * 4 + q];
        float4 wc = w4[(fb + 2) * 4 + q];
        float4 wd = w4[(fb + 3) * 4 + q];
        ax = fmaf(u.x, wa.x, ax); ay = fmaf(u.x, wa.y, ay);
        az = fmaf(u.x, wa.z, az); aw = fmaf(u.x, wa.w, aw);
        ax = fmaf(u.y, wb.x, ax); ay = fmaf(u.y, wb.y, ay);
        az = fmaf(u.y, wb.z, az); aw = fmaf(u.y, wb.w, aw);
        ax = fmaf(u.z, wc.x, ax); ay = fmaf(u.z, wc.y, ay);
        az = fmaf(u.z, wc.z, az); aw = fmaf(u.z, wc.w, aw);
        ax = fmaf(u.w, wd.x, ax); ay = fmaf(u.w, wd.y, ay);
        az = fmaf(u.w, wd.z, az); aw = fmaf(u.w, wd.w, aw);
    }
    float di = dinv[n];
    uint2 o;
    o.x = pack_bf2(ax * di, ay * di);
    o.y = pack_bf2(az * di, aw * di);
    ((uint2*)(hs + (size_t)n * 16))[q] = o;
}

// ---------------- fused layer-1 gather + ReLU + W2 projection ----------------
// One wave per node: 4 lanes/edge (uint2 = 4 bf16 chans) x 16 edge groups.
__global__ __launch_bounds__(256) void k_agg1h2(const int* __restrict__ rp,
                                                const int* __restrict__ csr,
                                                const u16* __restrict__ hs,
                                                const float* __restrict__ dinv,
                                                const float* __restrict__ W2,
                                                const float* __restrict__ b1,
                                                float* __restrict__ h2s, int N) {
    int wid = blockIdx.x * 4 + (threadIdx.x >> 6);
    int lane = threadIdx.x & 63;
    if (wid >= N) return;
    int beg = rp[wid], end = rp[wid + 1];
    int c4 = lane & 3, g = lane >> 2;              // channel quad, edge group
    float ax = 0.f, ay = 0.f, az = 0.f, aw = 0.f;
    for (int j = beg + g; j < end; j += 16) {
        int s = csr[j];
        uint2 u = ((const uint2*)(hs + (size_t)s * 16))[c4];
        ax += bflo(u.x); ay += bfhi(u.x);
        az += bflo(u.y); aw += bfhi(u.y);
    }
    #pragma unroll
    for (int m = 4; m <= 32; m <<= 1) {
        ax += __shfl_xor(ax, m); ay += __shfl_xor(ay, m);
        az += __shfl_xor(az, m); aw += __shfl_xor(aw, m);
    }
    uint2 su = ((const uint2*)(hs + (size_t)wid * 16))[c4];   // self term
    ax += bflo(su.x); ay += bfhi(su.x);
    az += bflo(su.y); aw += bfhi(su.y);
    float di = dinv[wid];
    float4 bq = ((const float4*)b1)[c4];
    float vx = fmaxf(fmaf(di, ax, bq.x), 0.f);
    float vy = fmaxf(fmaf(di, ay, bq.y), 0.f);
    float vz = fmaxf(fmaf(di, az, bq.z), 0.f);
    float vw = fmaxf(fmaf(di, aw, bq.w), 0.f);
    // W2[16,2] row-major: float4 pair covers channels 4c4..4c4+3, both cols
    float4 pa = ((const float4*)W2)[2 * c4];
    float4 pb = ((const float4*)W2)[2 * c4 + 1];
    float p0 = vx * pa.x + vy * pa.z + vz * pb.x + vw * pb.z;
    float p1 = vx * pa.y + vy * pa.w + vz * pb.y + vw * pb.w;
    p0 += __shfl_xor(p0, 1); p1 += __shfl_xor(p1, 1);
    p0 += __shfl_xor(p0, 2); p1 += __shfl_xor(p1, 2);
    if (lane == 0)
        *(float2*)(h2s + (size_t)wid * 2) = make_float2(p0 * di, p1 * di);
}

// ---------------- layer-2 gather -> out ----------------
// One wave per node: lane per edge, float2.
__global__ __launch_bounds__(256) void k_agg2(const int* __restrict__ rp,
                                              const int* __restrict__ csr,
                                              const float* __restrict__ h2s,
                                              const float* __restrict__ dinv,
                                              const float* __restrict__ b2,
                                              float* __restrict__ out, int N) {
    int wid = blockIdx.x * 4 + (threadIdx.x >> 6);
    int lane = threadIdx.x & 63;
    if (wid >= N) return;
    int beg = rp[wid], end = rp[wid + 1];
    float a0 = 0.f, a1 = 0.f;
    for (int j = beg + lane; j < end; j += 64) {
        int s = csr[j];
        float2 v = *(const float2*)(h2s + (size_t)s * 2);
        a0 += v.x; a1 += v.y;
    }
    #pragma unroll
    for (int m = 1; m <= 32; m <<= 1) {
        a0 += __shfl_xor(a0, m); a1 += __shfl_xor(a1, m);
    }
    if (lane == 0) {
        float di = dinv[wid];
        float2 sv = *(const float2*)(h2s + (size_t)wid * 2);
        *(float2*)(out + (size_t)wid * 2) =
            make_float2(fmaf(di, a0 + sv.x, b2[0]), fmaf(di, a1 + sv.y, b2[1]));
    }
}

extern "C" void kernel_launch(void* const* d_in, const int* in_sizes, int n_in,
                              void* d_out, int out_size, void* d_ws, size_t ws_size,
                              hipStream_t stream) {
    const float* x  = (const float*)d_in[0];
    const int*   ei = (const int*)d_in[1];
    const float* W1 = (const float*)d_in[2];
    const float* b1 = (const float*)d_in[3];
    const float* W2 = (const float*)d_in[4];
    const float* b2 = (const float*)d_in[5];
    float* out = (float*)d_out;

    const int N = in_sizes[0] / 128;      // 100000
    const int E = in_sizes[1] / 2;        // 3200000
    const int NBUK = (N + 255) / 256;     // 391 (<= 512)
    const int NPB  = (E + EPB - 1) / EPB; // 391

    char* ws = (char*)d_ws;
    size_t off = 0;
    auto alloc = [&](size_t bytes) {
        void* p = ws + off;
        off = (off + bytes + 255) & ~(size_t)255;
        return p;
    };
    u32*   part  = (u32*)alloc((size_t)E * 4);       // partition buf == csr
    int*   rp    = (int*)alloc((size_t)(N + 1) * 4);
    float* dinv  = (float*)alloc((size_t)N * 4);
    u16*   hs    = (u16*)alloc((size_t)N * 16 * 2);  // bf16
    float* h2s   = (float*)alloc((size_t)N * 2 * 4);
    int*   gcnt  = (int*)alloc((size_t)NBUK * 4);
    int*   gbase = (int*)alloc((size_t)NBUK * 4);
    int*   gcur  = (int*)alloc((size_t)NBUK * 4);

    dim3 B(256);
    k_bzero  <<<dim3(1),          dim3(512), 0, stream>>>(gcnt, NBUK);
    k_count  <<<dim3(NPB),                B, 0, stream>>>(ei + E, gcnt, E, NBUK);
    k_bscan  <<<dim3(1),          dim3(512), 0, stream>>>(gcnt, gbase, gcur, rp, N, E, NBUK);
    k_scatter<<<dim3(NPB),        dim3(512), 0, stream>>>(ei, gcur, part, E, NBUK);
    k_fillB  <<<dim3(NBUK),               B, 0, stream>>>(part, gbase, gcnt, rp, dinv, N);
    k_xw1    <<<dim3((N * 4 + 255) / 256),B, 0, stream>>>(x, W1, dinv, hs, N);
    k_agg1h2 <<<dim3((N + 3) / 4),        B, 0, stream>>>(rp, (const int*)part, hs, dinv, W2, b1, h2s, N);
    k_agg2   <<<dim3((N + 3) / 4),        B, 0, stream>>>(rp, (const int*)part, h2s, dinv, b2, out, N);
}